// Round 5
// baseline (194.692 us; speedup 1.0000x reference)
//
#include <hip/hip_runtime.h>
#include <hip/hip_bf16.h>
#include <hip/hip_cooperative_groups.h>

namespace cg = cooperative_groups;

#define TOK_T 8
#define TOK_H 32
#define TOK_W 32
#define NTOK 8192      // tokens per batch
#define BATCH 2
#define DMODEL 256
#define D3 768
#define NHEADS 8
#define DHEAD 32

using short8  = __attribute__((ext_vector_type(8))) short;
using ushort8 = __attribute__((ext_vector_type(8))) unsigned short;
using f32x4   = __attribute__((ext_vector_type(4))) float;

__device__ __forceinline__ ushort f2bf(float f) {
  union { float f; unsigned u; } v; v.f = f;
  unsigned u = v.u;
  unsigned r = (u + 0x7FFFu + ((u >> 16) & 1u)) >> 16;
  return (ushort)r;
}
__device__ __forceinline__ float bf2f(ushort u) {
  union { unsigned u; float f; } v; v.u = ((unsigned)u) << 16;
  return v.f;
}

// ---------------- 128x128 GEMM tile, C = A[.,256] * B[.,256]^T ----------------
// 512 threads, 8 waves (4x2 of 32x64), K=256, BK=32, double-buffered LDS.
// A/B staged via registers (converting f32->bf16 on the fly when needed),
// written to LDS in the slot-swizzled layout ck = r*4 + (k ^ ((r>>1)&3)).
// sm: 2 bufs x 8192 ushorts (A at +0, B at +4096 within each buf) = 32 KB.
template<bool AF32, bool BF32, bool OUTBF16>
__device__ __forceinline__ void gemm128(const void* __restrict__ Av,
                                        const void* __restrict__ Bv,
                                        void* __restrict__ Cv,
                                        int bm, int bn, int ldc,
                                        ushort* __restrict__ sm) {
  const int tid  = threadIdx.x;
  const int lane = tid & 63;
  const int wid  = tid >> 6;
  const int wr   = wid >> 1;      // 0..3 (rows of 32)
  const int wc   = wid & 1;       // 0..1 (cols of 64)
  const int fr   = lane & 15;
  const int kb   = lane >> 4;
  const int sr   = tid >> 2;      // staging row 0..127
  const int sk   = tid & 3;       // staging slot 0..3
  const int sck  = sr * 4 + (sk ^ ((sr >> 1) & 3));  // swizzled slot

  f32x4 acc[2][4] = {};

  float4 a0, a1, b0, b1;
  ushort8 a16, b16;

  auto load = [&](int kt) {
    if constexpr (AF32) {
      const float* Ap = (const float*)Av + (size_t)(bm + sr) * 256 + kt + sk * 8;
      a0 = *(const float4*)Ap;
      a1 = *(const float4*)(Ap + 4);
    } else {
      a16 = *(const ushort8*)((const ushort*)Av + (size_t)(bm + sr) * 256 + kt + sk * 8);
    }
    if constexpr (BF32) {
      const float* Bp = (const float*)Bv + (size_t)(bn + sr) * 256 + kt + sk * 8;
      b0 = *(const float4*)Bp;
      b1 = *(const float4*)(Bp + 4);
    } else {
      b16 = *(const ushort8*)((const ushort*)Bv + (size_t)(bn + sr) * 256 + kt + sk * 8);
    }
  };
  auto stow = [&](int buf) {
    ushort8 av, bv;
    if constexpr (AF32) {
      av[0] = f2bf(a0.x); av[1] = f2bf(a0.y); av[2] = f2bf(a0.z); av[3] = f2bf(a0.w);
      av[4] = f2bf(a1.x); av[5] = f2bf(a1.y); av[6] = f2bf(a1.z); av[7] = f2bf(a1.w);
    } else av = a16;
    if constexpr (BF32) {
      bv[0] = f2bf(b0.x); bv[1] = f2bf(b0.y); bv[2] = f2bf(b0.z); bv[3] = f2bf(b0.w);
      bv[4] = f2bf(b1.x); bv[5] = f2bf(b1.y); bv[6] = f2bf(b1.z); bv[7] = f2bf(b1.w);
    } else bv = b16;
    *(ushort8*)&sm[buf * 8192 + sck * 8] = av;
    *(ushort8*)&sm[buf * 8192 + 4096 + sck * 8] = bv;
  };

  load(0);
  stow(0);
  __syncthreads();

  for (int it = 0; it < 8; ++it) {
    const int cur = it & 1;
    if (it < 7) load((it + 1) * 32);   // issue next-tile global loads early (T14)

    short8 af[2], bf8[4];
#pragma unroll
    for (int m = 0; m < 2; ++m) {
      int r  = wr * 32 + m * 16 + fr;
      int ck = r * 4 + (kb ^ ((r >> 1) & 3));
      af[m] = *(const short8*)&sm[cur * 8192 + ck * 8];
    }
#pragma unroll
    for (int n = 0; n < 4; ++n) {
      int r  = wc * 64 + n * 16 + fr;
      int ck = r * 4 + (kb ^ ((r >> 1) & 3));
      bf8[n] = *(const short8*)&sm[cur * 8192 + 4096 + ck * 8];
    }
#pragma unroll
    for (int m = 0; m < 2; ++m)
#pragma unroll
      for (int n = 0; n < 4; ++n)
        acc[m][n] = __builtin_amdgcn_mfma_f32_16x16x32_bf16(af[m], bf8[n], acc[m][n], 0, 0, 0);

    if (it < 7) stow(cur ^ 1);   // write next buffer (current buf reads already consumed)
    __syncthreads();
  }

  // epilogue: C/D layout col=lane&15, row=(lane>>4)*4+j
  if constexpr (OUTBF16) {
    ushort* C = (ushort*)Cv;
#pragma unroll
    for (int m = 0; m < 2; ++m)
#pragma unroll
      for (int n = 0; n < 4; ++n)
#pragma unroll
        for (int j = 0; j < 4; ++j) {
          int row = bm + wr * 32 + m * 16 + kb * 4 + j;
          int col = bn + wc * 64 + n * 16 + fr;
          C[(size_t)row * ldc + col] = f2bf(acc[m][n][j]);
        }
  } else {
    float* C = (float*)Cv;
#pragma unroll
    for (int m = 0; m < 2; ++m)
#pragma unroll
      for (int n = 0; n < 4; ++n)
#pragma unroll
        for (int j = 0; j < 4; ++j) {
          int row = bm + wr * 32 + m * 16 + kb * 4 + j;
          int col = bn + wc * 64 + n * 16 + fr;
          C[(size_t)row * ldc + col] = acc[m][n][j];
        }
  }
}

// ---------------- local attention unit (256 threads = 1 token each) ----------------
// unit = (b, head, 4x8x8 spatial tile); halo 6x10x10 = 600 tokens, KP=40 rows.
// sh: 24000 ushorts (48 KB), reused K -> V.
#define NHALO 600
#define KP 40

__device__ __forceinline__ void attn_unit(const ushort* __restrict__ qkv,
                                          ushort* __restrict__ aob,
                                          int unit, int stid,
                                          ushort* __restrict__ sh) {
  const int b    = unit >> 8;
  const int rem  = unit & 255;
  const int head = rem >> 5;
  const int tile = rem & 31;
  const int tz = tile >> 4;
  const int ty = (tile >> 2) & 3;
  const int tx = tile & 3;
  const int t0 = tz * 4, h0 = ty * 8, w0 = tx * 8;

  auto stage = [&](int ofs) {   // ofs = DMODEL for K, 2*DMODEL for V
    for (int idx = stid; idx < NHALO; idx += 256) {
      int ht  = idx / 100;
      int rem2 = idx - ht * 100;
      int hh  = rem2 / 10;
      int hw  = rem2 - hh * 10;
      int gt = t0 - 1 + ht, gh = h0 - 1 + hh, gw = w0 - 1 + hw;
      ushort8* dst = (ushort8*)&sh[idx * KP];
      if (gt >= 0 && gt < TOK_T && gh >= 0 && gh < TOK_H && gw >= 0 && gw < TOK_W) {
        size_t base = ((size_t)b * NTOK + (size_t)gt * 1024 + gh * 32 + gw) * D3;
        const ushort8* s = (const ushort8*)(qkv + base + ofs + head * DHEAD);
#pragma unroll
        for (int p = 0; p < 4; ++p) dst[p] = s[p];
      } else {
        ushort8 z = (ushort8)0;
#pragma unroll
        for (int p = 0; p < 4; ++p) dst[p] = z;
      }
    }
  };

  // ---- stage K ----
  stage(DMODEL);

  const int tt = stid >> 6;
  const int th = (stid >> 3) & 7;
  const int tw = stid & 7;
  const int n  = (t0 + tt) * 1024 + (h0 + th) * 32 + (w0 + tw);

  const ushort* qp = qkv + ((size_t)b * NTOK + n) * D3 + head * DHEAD;
  float q[DHEAD];
  {
    const ushort8* qs = (const ushort8*)qp;
#pragma unroll
    for (int p = 0; p < 4; ++p) {
      ushort8 v = qs[p];
#pragma unroll
      for (int e = 0; e < 8; ++e) q[p * 8 + e] = bf2f(v[e]);
    }
  }
  __syncthreads();

  // ---- scores ----
  const float scale = 0.1767766952966369f;  // 1/sqrt(32)
  float s[27];
#pragma unroll
  for (int nb = 0; nb < 27; ++nb) {
    int dt = nb / 9, dh = (nb / 3) % 3, dw = nb % 3;
    int hidx = (tt + dt) * 100 + (th + dh) * 10 + (tw + dw);
    const ushort8* kp = (const ushort8*)&sh[hidx * KP];
    float a = 0.f;
#pragma unroll
    for (int p = 0; p < 4; ++p) {
      ushort8 kk = kp[p];
#pragma unroll
      for (int e = 0; e < 8; ++e) a += q[p * 8 + e] * bf2f(kk[e]);
    }
    s[nb] = a * scale;
  }
  __syncthreads();   // all K reads done before V overwrites

  // ---- stage V (same buffer) ----
  stage(2 * DMODEL);

  float mx = s[0];
#pragma unroll
  for (int nb = 1; nb < 27; ++nb) mx = fmaxf(mx, s[nb]);
  __syncthreads();

  // ---- softmax + PV ----
  float o[DHEAD] = {};
  float sum = 0.f;
#pragma unroll
  for (int nb = 0; nb < 27; ++nb) {
    int dt = nb / 9, dh = (nb / 3) % 3, dw = nb % 3;
    int hidx = (tt + dt) * 100 + (th + dh) * 10 + (tw + dw);
    const ushort8* vp = (const ushort8*)&sh[hidx * KP];
    float p = __expf(s[nb] - mx);
    sum += p;
#pragma unroll
    for (int c = 0; c < 4; ++c) {
      ushort8 vv = vp[c];
#pragma unroll
      for (int e = 0; e < 8; ++e) o[c * 8 + e] += p * bf2f(vv[e]);
    }
  }

  float inv = 1.f / sum;
  ushort8 os[4];
#pragma unroll
  for (int c = 0; c < 4; ++c)
#pragma unroll
    for (int e = 0; e < 8; ++e) os[c][e] = f2bf(o[c * 8 + e] * inv);
  ushort8* op = (ushort8*)(aob + ((size_t)b * NTOK + n) * DMODEL + head * DHEAD);
#pragma unroll
  for (int c = 0; c < 4; ++c) op[c] = os[c];
}

// ---------------- cooperative mega-kernel: gemm1 -> attn -> gemm2 ----------------
// 256 blocks x 512 threads; 96 KB LDS -> 1 block/CU, fully co-resident.
// Phase 1: qkv = x @ w_qkv^T  (768 tiles of 128x128, 3 per block; consecutive
//          units share the A-panel -> A stays in this XCD's L2).
// Phase 2: attention, 512 units, 2 sub-units per block (tid>>8).
// Phase 3: out = attn_out @ w_out^T (256 tiles, 1 per block).
__global__ __launch_bounds__(512, 1) void mega(const float* __restrict__ x,
                                               const float* __restrict__ wq,
                                               const float* __restrict__ wo,
                                               ushort* __restrict__ qkv,
                                               ushort* __restrict__ aob,
                                               float* __restrict__ out) {
  __shared__ __align__(16) ushort sm[48000];   // 96 KB: gemm uses 32 KB, attn 2x48 KB
  const int blk = blockIdx.x;
  cg::grid_group grid = cg::this_grid();

#pragma unroll 1
  for (int r = 0; r < 3; ++r) {
    int u = blk * 3 + r;
    gemm128<true, true, true>(x, wq, qkv, (u / 6) * 128, (u % 6) * 128, D3, sm);
  }
  grid.sync();

  attn_unit(qkv, aob, blk * 2 + (threadIdx.x >> 8), threadIdx.x & 255,
            sm + (threadIdx.x >> 8) * (NHALO * KP));
  grid.sync();

  gemm128<false, true, false>(aob, wo, out, (blk >> 1) * 128, (blk & 1) * 128, DMODEL, sm);
}

// ---------------- launch ----------------
extern "C" void kernel_launch(void* const* d_in, const int* in_sizes, int n_in,
                              void* d_out, int out_size, void* d_ws, size_t ws_size,
                              hipStream_t stream) {
  const float* x     = (const float*)d_in[0];
  const float* w_qkv = (const float*)d_in[1];
  const float* w_out = (const float*)d_in[2];
  float* out = (float*)d_out;

  char* ws = (char*)d_ws;
  ushort* qkvb = (ushort*)ws;                                   // 24 MB
  ushort* aob  = (ushort*)(ws + (size_t)BATCH * NTOK * D3 * 2); // 8 MB

  void* args[6] = {(void*)&x, (void*)&w_qkv, (void*)&w_out,
                   (void*)&qkvb, (void*)&aob, (void*)&out};
  hipLaunchCooperativeKernel((const void*)mega, dim3(256), dim3(512), args, 0u, stream);
}